// Round 6
// baseline (3077.880 us; speedup 1.0000x reference)
//
#include <hip/hip_runtime.h>

#define TT 2000
#define BB 128
#define DD 64
#define UU 128
#define G3U 384          // 3*U
#define NROW (BB * TT)

// ---------- types ----------
typedef __attribute__((ext_vector_type(8))) short bf16x8;  // 8 bf16 (4 VGPRs)
typedef __attribute__((ext_vector_type(4))) float f4v;     // 4 f32

#define MFMA16(A, B, C) __builtin_amdgcn_mfma_f32_16x16x32_bf16((A), (B), (C), 0, 0, 0)

// ---------- helpers ----------
static __device__ __forceinline__ short f2bf(float f) {  // RNE f32 -> bf16
  unsigned u = __float_as_uint(f);
  unsigned r = (u + 0x7FFFu + ((u >> 16) & 1u)) >> 16;
  return (short)(unsigned short)r;
}
static __device__ __forceinline__ float bf2f(short h) {
  return __uint_as_float(((unsigned)(unsigned short)h) << 16);
}
static __device__ __forceinline__ unsigned pack2(short a, short b) {
  return (unsigned)(unsigned short)a | ((unsigned)(unsigned short)b << 16);
}
__device__ __forceinline__ float sig_(float v) {  // exact at +-inf
  float e = __builtin_amdgcn_exp2f(-1.442695041f * v);
  return __builtin_amdgcn_rcpf(1.0f + e);
}
__device__ __forceinline__ float tanh_(float v) {
  float e = __builtin_amdgcn_exp2f(-2.885390082f * v);
  float r = __builtin_amdgcn_rcpf(1.0f + e);
  return fmaf(2.0f, r, -1.0f);
}
// LDS-only barrier: no vmcnt(0) drain, so gx prefetch loads and out stores
// stay in flight across steps. sched_barrier fences hoisting (rule #18).
__device__ __forceinline__ void bar_lds() {
  __builtin_amdgcn_sched_barrier(0);
  asm volatile("s_waitcnt lgkmcnt(0)" ::: "memory");
  __builtin_amdgcn_s_barrier();
  __builtin_amdgcn_sched_barrier(0);
}

__device__ __forceinline__ float4 fma4(float s, float4 w, float4 a) {
  a.x = fmaf(s, w.x, a.x);
  a.y = fmaf(s, w.y, a.y);
  a.z = fmaf(s, w.z, a.z);
  a.w = fmaf(s, w.w, a.w);
  return a;
}

// ---------- prologue: gx[r][c] = sum_k x[r][k]*(kern[k][c]+akern[k][c]) + bias[c] ----------
// fp32 exact (keeps the input-side path out of the bf16 error budget).
__global__ __launch_bounds__(256, 2)
void gx_kernel(const float* __restrict__ x, const float* __restrict__ kern,
               const float* __restrict__ akern, const float* __restrict__ bias,
               float* __restrict__ gx) {
  __shared__ __align__(16) float xT[64][68];
  __shared__ __align__(16) float Ws[64][68];
  const int r0 = blockIdx.x * 64;
  const int c0 = blockIdx.y * 64;
  const int tid = threadIdx.x;

  {
    const int row = tid >> 2;
    const int kb = (tid & 3) * 16;
#pragma unroll
    for (int i = 0; i < 4; ++i) {
      float4 v = *(const float4*)&x[(size_t)(r0 + row) * DD + kb + i * 4];
      xT[kb + i * 4 + 0][row] = v.x;
      xT[kb + i * 4 + 1][row] = v.y;
      xT[kb + i * 4 + 2][row] = v.z;
      xT[kb + i * 4 + 3][row] = v.w;
    }
    const int kk = tid >> 2;
    const int jb = (tid & 3) * 16;
#pragma unroll
    for (int i = 0; i < 4; ++i) {
      const size_t off = (size_t)kk * G3U + c0 + jb + i * 4;
      float4 a = *(const float4*)&kern[off];
      float4 c = *(const float4*)&akern[off];
      *(float4*)&Ws[kk][jb + i * 4] = make_float4(a.x + c.x, a.y + c.y, a.z + c.z, a.w + c.w);
    }
  }
  __syncthreads();

  const int tx = tid & 15, ty = tid >> 4;
  float4 acc0 = make_float4(0, 0, 0, 0), acc1 = acc0, acc2 = acc0, acc3 = acc0;
#pragma unroll
  for (int k = 0; k < 64; ++k) {
    float4 wv = *(const float4*)&Ws[k][tx * 4];
    float4 xv = *(const float4*)&xT[k][ty * 4];
    acc0 = fma4(xv.x, wv, acc0);
    acc1 = fma4(xv.y, wv, acc1);
    acc2 = fma4(xv.z, wv, acc2);
    acc3 = fma4(xv.w, wv, acc3);
  }
  float4 bv = *(const float4*)&bias[c0 + tx * 4];
  acc0.x += bv.x; acc0.y += bv.y; acc0.z += bv.z; acc0.w += bv.w;
  acc1.x += bv.x; acc1.y += bv.y; acc1.z += bv.z; acc1.w += bv.w;
  acc2.x += bv.x; acc2.y += bv.y; acc2.z += bv.z; acc2.w += bv.w;
  acc3.x += bv.x; acc3.y += bv.y; acc3.z += bv.z; acc3.w += bv.w;
  float* g0 = &gx[(size_t)(r0 + ty * 4) * G3U + c0 + tx * 4];
  *(float4*)(g0 + 0 * G3U) = acc0;
  *(float4*)(g0 + 1 * G3U) = acc1;
  *(float4*)(g0 + 2 * G3U) = acc2;
  *(float4*)(g0 + 3 * G3U) = acc3;
}

// ---------- recurrence via MFMA ----------
// 8 blocks x 16 batch rows, 256 threads = 4 waves.
// Transposed GEMM: D = W^T (gates x K) * H^T (K x 16 batch).
//   A-frag (weights, VGPR-resident): elem e of (M-tile mt, K-tile kt) =
//       W[32kt + 8*(lane>>4) + e][16*mt + (lane&15)]   (bf16)
//   B-frag: H^T[32kt + 8*(lane>>4)+e][lane&15] = h[batch=lane&15][k] -> 1 ds_read_b128
//   C/D (verified layout): col = lane&15 = batch, row = 4*(lane>>4)+i = gate col in tile.
// Wave w owns z cols 32w..32w+32, r cols 128+same, hh cols same -> z, r, h_prev,
// rh, blend all LANE-LOCAL. gx arrives as C-init from prefetched dwordx4 loads.
// Precision: h and rh are hi+lo bf16 (2x K, same weight frags) so the recurrent
// feedback path is ~fp32; only the bf16 weight quantization remains.
__global__ __launch_bounds__(256, 1)
void gru_mfma(const float* __restrict__ gx, const float* __restrict__ rk,
              const float* __restrict__ h0, float* __restrict__ out) {
  const int tid = threadIdx.x;
  const int w = tid >> 6;        // wave 0..3
  const int lane = tid & 63;
  const int l15 = lane & 15;     // batch-within-block (B/C cols); A row
  const int lg = lane >> 4;      // 0..3
  const int b0 = blockIdx.x * 16;

  // [hi/lo][batch][k]; 136-short rows: 16B-aligned b128, banks at the 8-cyc floor
  __shared__ short Hlds[2][16][136];
  __shared__ short Rlds[2][16][136];

  // ---- weight A-frags (one-time gather) ----
  bf16x8 aZ[2][4], aR[2][4], aH[2][4];
#pragma unroll
  for (int u = 0; u < 2; ++u)
#pragma unroll
    for (int kt = 0; kt < 4; ++kt) {
      bf16x8 z8, r8, h8;
#pragma unroll
      for (int e = 0; e < 8; ++e) {
        const size_t krow = (size_t)(32 * kt + 8 * lg + e) * G3U;
        const int c = 32 * w + 16 * u + l15;
        z8[e] = f2bf(rk[krow + c]);
        r8[e] = f2bf(rk[krow + 128 + c]);
        h8[e] = f2bf(rk[krow + 256 + c]);
      }
      aZ[u][kt] = z8;
      aR[u][kt] = r8;
      aH[u][kt] = h8;
    }

  float hprev[2][4];
#pragma unroll
  for (int u = 0; u < 2; ++u)
#pragma unroll
    for (int i = 0; i < 4; ++i)
      hprev[u][i] = h0[(size_t)(b0 + l15) * UU + 32 * w + 16 * u + 4 * lg + i];

  {  // Hlds init (hi/lo split of h0)
    const int r = tid >> 4, c0 = (tid & 15) * 8;
#pragma unroll
    for (int e = 0; e < 8; ++e) {
      float v = h0[(size_t)(b0 + r) * UU + c0 + e];
      short hi = f2bf(v);
      Hlds[0][r][c0 + e] = hi;
      Hlds[1][r][c0 + e] = f2bf(v - bf2f(hi));
    }
  }

  const float* gxl = gx + (size_t)(b0 + l15) * TT * G3U + 4 * lg;
  float* outl = out + (size_t)(b0 + l15) * TT * UU + 32 * w + 4 * lg;

  f4v pz0[2], pr0[2], ph0_[2], pz1[2], pr1[2], ph1_[2];
#define LOADSET(T, PZ, PR, PH)                          \
  do {                                                  \
    const float* gp_ = gxl + (size_t)(T)*G3U;           \
    PZ[0] = *(const f4v*)(gp_ + 32 * w);                \
    PZ[1] = *(const f4v*)(gp_ + 32 * w + 16);           \
    PR[0] = *(const f4v*)(gp_ + 128 + 32 * w);          \
    PR[1] = *(const f4v*)(gp_ + 128 + 32 * w + 16);     \
    PH[0] = *(const f4v*)(gp_ + 256 + 32 * w);          \
    PH[1] = *(const f4v*)(gp_ + 256 + 32 * w + 16);     \
  } while (0)

  LOADSET(0, pz0, pr0, ph0_);
  LOADSET(1, pz1, pr1, ph1_);
  bar_lds();  // Hlds init visible

#define STEP(T, PZ, PR, PH)                                                   \
  do {                                                                        \
    f4v cz_[2] = {PZ[0], PZ[1]};                                              \
    f4v cr_[2] = {PR[0], PR[1]};                                              \
    f4v cgh_[2] = {PH[0], PH[1]};                                             \
    if ((T) + 2 < TT) LOADSET((T) + 2, PZ, PR, PH);                           \
    /* phase 1: z, r */                                                       \
    bf16x8 bhhi_[4], bhlo_[4];                                                \
    _Pragma("unroll") for (int kt = 0; kt < 4; ++kt) {                        \
      bhhi_[kt] = *(const bf16x8*)&Hlds[0][l15][32 * kt + 8 * lg];            \
      bhlo_[kt] = *(const bf16x8*)&Hlds[1][l15][32 * kt + 8 * lg];            \
    }                                                                         \
    _Pragma("unroll") for (int kt = 0; kt < 4; ++kt) {                        \
      _Pragma("unroll") for (int u = 0; u < 2; ++u) {                         \
        cz_[u] = MFMA16(aZ[u][kt], bhhi_[kt], cz_[u]);                        \
        cz_[u] = MFMA16(aZ[u][kt], bhlo_[kt], cz_[u]);                        \
        cr_[u] = MFMA16(aR[u][kt], bhhi_[kt], cr_[u]);                        \
        cr_[u] = MFMA16(aR[u][kt], bhlo_[kt], cr_[u]);                        \
      }                                                                       \
    }                                                                         \
    float zz_[2][4], rh_[2][4];                                               \
    _Pragma("unroll") for (int u = 0; u < 2; ++u) {                           \
      _Pragma("unroll") for (int i = 0; i < 4; ++i) {                         \
        zz_[u][i] = sig_(cz_[u][i]);                                          \
        rh_[u][i] = sig_(cr_[u][i]) * hprev[u][i];                            \
      }                                                                       \
    }                                                                         \
    _Pragma("unroll") for (int u = 0; u < 2; ++u) {                           \
      _Pragma("unroll") for (int p = 0; p < 2; ++p) {                         \
        const int c0_ = 32 * w + 16 * u + 4 * lg + 2 * p;                     \
        short a_ = f2bf(rh_[u][2 * p]), b_ = f2bf(rh_[u][2 * p + 1]);         \
        *(unsigned*)&Rlds[0][l15][c0_] = pack2(a_, b_);                       \
        *(unsigned*)&Rlds[1][l15][c0_] =                                      \
            pack2(f2bf(rh_[u][2 * p] - bf2f(a_)),                             \
                  f2bf(rh_[u][2 * p + 1] - bf2f(b_)));                        \
      }                                                                       \
    }                                                                         \
    bar_lds(); /* B1: rh published */                                         \
    /* phase 2: hh, blend, publish h */                                       \
    bf16x8 brhi_[4], brlo_[4];                                                \
    _Pragma("unroll") for (int kt = 0; kt < 4; ++kt) {                        \
      brhi_[kt] = *(const bf16x8*)&Rlds[0][l15][32 * kt + 8 * lg];            \
      brlo_[kt] = *(const bf16x8*)&Rlds[1][l15][32 * kt + 8 * lg];            \
    }                                                                         \
    _Pragma("unroll") for (int kt = 0; kt < 4; ++kt) {                        \
      _Pragma("unroll") for (int u = 0; u < 2; ++u) {                         \
        cgh_[u] = MFMA16(aH[u][kt], brhi_[kt], cgh_[u]);                      \
        cgh_[u] = MFMA16(aH[u][kt], brlo_[kt], cgh_[u]);                      \
      }                                                                       \
    }                                                                         \
    float* op_ = outl + (size_t)(T)*UU;                                       \
    _Pragma("unroll") for (int u = 0; u < 2; ++u) {                           \
      float hn_[4];                                                           \
      _Pragma("unroll") for (int i = 0; i < 4; ++i) {                         \
        float hh_ = tanh_(cgh_[u][i]);                                        \
        hn_[i] = fmaf(zz_[u][i], hprev[u][i] - hh_, hh_);                     \
        hprev[u][i] = hn_[i];                                                 \
      }                                                                       \
      *(f4v*)(op_ + 16 * u) = (f4v){hn_[0], hn_[1], hn_[2], hn_[3]};          \
      _Pragma("unroll") for (int p = 0; p < 2; ++p) {                         \
        const int c0_ = 32 * w + 16 * u + 4 * lg + 2 * p;                     \
        short a_ = f2bf(hn_[2 * p]), b_ = f2bf(hn_[2 * p + 1]);               \
        *(unsigned*)&Hlds[0][l15][c0_] = pack2(a_, b_);                       \
        *(unsigned*)&Hlds[1][l15][c0_] =                                      \
            pack2(f2bf(hn_[2 * p] - bf2f(a_)),                               \
                  f2bf(hn_[2 * p + 1] - bf2f(b_)));                           \
      }                                                                       \
    }                                                                         \
    bar_lds(); /* B2: h published */                                          \
  } while (0)

  for (int t = 0; t < TT; t += 2) {
    STEP(t, pz0, pr0, ph0_);
    STEP(t + 1, pz1, pr1, ph1_);
  }
#undef STEP
#undef LOADSET
}

extern "C" void kernel_launch(void* const* d_in, const int* in_sizes, int n_in,
                              void* d_out, int out_size, void* d_ws, size_t ws_size,
                              hipStream_t stream) {
  const float* x = (const float*)d_in[0];
  const float* kern = (const float*)d_in[1];
  const float* rk = (const float*)d_in[2];
  const float* akern = (const float*)d_in[3];
  // d_in[4] attention_w, d_in[5] attention_u, d_in[7] attention_b, d_in[8] attention_v:
  // mathematically dead (softmax over singleton axis == 1, so z_hat == x_t).
  const float* bias = (const float*)d_in[6];
  const float* h0 = (const float*)d_in[9];
  float* out = (float*)d_out;
  float* gx = (float*)d_ws;  // [NROW][384] fp32 = 393,216,000 bytes

  gx_kernel<<<dim3(NROW / 64, G3U / 64), 256, 0, stream>>>(x, kern, akern, bias, gx);
  gru_mfma<<<dim3(BB / 16), 256, 0, stream>>>(gx, rk, h0, out);
}

// Round 9
// 2300.847 us; speedup vs baseline: 1.3377x; 1.3377x over previous
//
#include <hip/hip_runtime.h>

#define TT 2000
#define BB 128
#define DD 64
#define UU 128
#define G3U 384          // 3*U
#define NROW (BB * TT)   // 256000 rows of x / gx

typedef __attribute__((ext_vector_type(4))) float f4v;

// ---------- helpers ----------
__device__ __forceinline__ float4 fma4(float s, float4 w, float4 a) {
  a.x = fmaf(s, w.x, a.x);
  a.y = fmaf(s, w.y, a.y);
  a.z = fmaf(s, w.z, a.z);
  a.w = fmaf(s, w.w, a.w);
  return a;
}
// packed dual-FP32 FMA: acc.{x,y} += a.{x,y} * b.{x,y}
__device__ __forceinline__ void pk_fma(float2& acc, float2 a, float2 b) {
  asm("v_pk_fma_f32 %0, %1, %2, %0" : "+v"(acc) : "v"(a), "v"(b));
}
// DPP via builtin ONLY: the compiler's hazard recognizer inserts the required
// wait states for VALU-write -> DPP-read. Inline-asm DPP (rounds 7/8) hid the
// hazard from the compiler and silently corrupted the reduction.
template <int CTRL>
__device__ __forceinline__ float dpp_mov(float v) {
  return __int_as_float(__builtin_amdgcn_update_dpp(0, __float_as_int(v), CTRL, 0xF, 0xF, true));
}
// full sum across the 16 lanes of a group (after packed-pair sum)
__device__ __forceinline__ float red16(float2 a) {
  float v = a.x + a.y;
  v += dpp_mov<0xB1>(v);   // quad_perm [1,0,3,2] : lane ^ 1
  v += dpp_mov<0x4E>(v);   // quad_perm [2,3,0,1] : lane ^ 2
  v += dpp_mov<0x141>(v);  // row_half_mirror     : crosses quads within 8
  v += dpp_mov<0x140>(v);  // row_mirror          : crosses halves within 16
  return v;
}
__device__ __forceinline__ float sig_(float v) {  // exact at +-inf
  float e = __builtin_amdgcn_exp2f(-1.442695041f * v);
  return __builtin_amdgcn_rcpf(1.0f + e);
}
__device__ __forceinline__ float tanh_(float v) {
  float e = __builtin_amdgcn_exp2f(-2.885390082f * v);
  float r = __builtin_amdgcn_rcpf(1.0f + e);
  return fmaf(2.0f, r, -1.0f);
}
// LDS-only barrier: no vmcnt(0) drain -> gx prefetch loads / out stores stay
// in flight across steps. sched_barrier fences hoisting (rule #18).
__device__ __forceinline__ void bar_lds() {
  __builtin_amdgcn_sched_barrier(0);
  asm volatile("s_waitcnt lgkmcnt(0)" ::: "memory");
  __builtin_amdgcn_s_barrier();
  __builtin_amdgcn_sched_barrier(0);
}

// ---------- prologue: gx[r][c] = sum_k x[r][k]*(kern[k][c]+akern[k][c]) + bias[c] ----------
__global__ __launch_bounds__(256, 2)
void gx_kernel(const float* __restrict__ x, const float* __restrict__ kern,
               const float* __restrict__ akern, const float* __restrict__ bias,
               float* __restrict__ gx) {
  __shared__ __align__(16) float xT[64][68];
  __shared__ __align__(16) float Ws[64][68];
  const int r0 = blockIdx.x * 64;
  const int c0 = blockIdx.y * 64;
  const int tid = threadIdx.x;

  {
    const int row = tid >> 2;
    const int kb = (tid & 3) * 16;
#pragma unroll
    for (int i = 0; i < 4; ++i) {
      float4 v = *(const float4*)&x[(size_t)(r0 + row) * DD + kb + i * 4];
      xT[kb + i * 4 + 0][row] = v.x;
      xT[kb + i * 4 + 1][row] = v.y;
      xT[kb + i * 4 + 2][row] = v.z;
      xT[kb + i * 4 + 3][row] = v.w;
    }
    const int kk = tid >> 2;
    const int jb = (tid & 3) * 16;
#pragma unroll
    for (int i = 0; i < 4; ++i) {
      const size_t off = (size_t)kk * G3U + c0 + jb + i * 4;
      float4 a = *(const float4*)&kern[off];
      float4 c = *(const float4*)&akern[off];
      *(float4*)&Ws[kk][jb + i * 4] = make_float4(a.x + c.x, a.y + c.y, a.z + c.z, a.w + c.w);
    }
  }
  __syncthreads();

  const int tx = tid & 15, ty = tid >> 4;
  float4 acc0 = make_float4(0, 0, 0, 0), acc1 = acc0, acc2 = acc0, acc3 = acc0;
#pragma unroll
  for (int k = 0; k < 64; ++k) {
    float4 wv = *(const float4*)&Ws[k][tx * 4];
    float4 xv = *(const float4*)&xT[k][ty * 4];
    acc0 = fma4(xv.x, wv, acc0);
    acc1 = fma4(xv.y, wv, acc1);
    acc2 = fma4(xv.z, wv, acc2);
    acc3 = fma4(xv.w, wv, acc3);
  }
  float4 bv = *(const float4*)&bias[c0 + tx * 4];
  acc0.x += bv.x; acc0.y += bv.y; acc0.z += bv.z; acc0.w += bv.w;
  acc1.x += bv.x; acc1.y += bv.y; acc1.z += bv.z; acc1.w += bv.w;
  acc2.x += bv.x; acc2.y += bv.y; acc2.z += bv.z; acc2.w += bv.w;
  acc3.x += bv.x; acc3.y += bv.y; acc3.z += bv.z; acc3.w += bv.w;
  float* g0 = &gx[(size_t)(r0 + ty * 4) * G3U + c0 + tx * 4];
  *(float4*)(g0 + 0 * G3U) = acc0;
  *(float4*)(g0 + 1 * G3U) = acc1;
  *(float4*)(g0 + 2 * G3U) = acc2;
  *(float4*)(g0 + 3 * G3U) = acc3;
}

// ---------- recurrence ----------
// One block per batch row, 512 threads = 8 waves.
// Group = 16 lanes (one DPP row): g = tid>>4 (0..31), j = tid&15 owns k-slice
// [8j, 8j+8). Group g owns cols: z {4g..4g+4}, r {128+4g..}, hh {4g..}.
// fp32 LDS exchange. Layout [16][12] floats: slice j's two b128 reads put
// j=0..7 on all 32 banks once; j and j+8 are a 2-way different-address alias
// (free per m136); 4 groups/wave broadcast. 2 reads/lane/phase.
// Critical path: phase 1 computes ONLY the r-gate path to the rh write
// (z reduction+sigmoid deferred to phase 2, register-only there).
__global__ __launch_bounds__(512, 2)
void gru_rec(const float* __restrict__ gx, const float* __restrict__ rk,
             const float* __restrict__ h0, float* __restrict__ out) {
  const int b = blockIdx.x;
  const int tid = threadIdx.x;
  const int g = tid >> 4;        // 0..31
  const int j = tid & 15;        // k-slice index
  const int zc = 4 * g;          // owned column base

  __shared__ __align__(16) float Hb[16][12];  // h slice j at [j][0..8)
  __shared__ __align__(16) float Rb[16][12];  // r*h same layout

  const float* gxb = gx + (size_t)b * TT * G3U;
  float* outb = out + (size_t)b * TT * UU;

  // weights in VGPRs, packed along k: w?[c][m] = (rk[8j+2m][col], rk[8j+2m+1][col])
  float2 wZ[4][4], wR[4][4], wH[4][4];
#pragma unroll
  for (int c = 0; c < 4; ++c)
#pragma unroll
    for (int m = 0; m < 4; ++m) {
      const float* r0p = rk + (size_t)(8 * j + 2 * m) * G3U;
      const float* r1p = rk + (size_t)(8 * j + 2 * m + 1) * G3U;
      wZ[c][m] = make_float2(r0p[zc + c], r1p[zc + c]);
      wR[c][m] = make_float2(r0p[128 + zc + c], r1p[128 + zc + c]);
      wH[c][m] = make_float2(r0p[256 + zc + c], r1p[256 + zc + c]);
    }

  // fp32 recurrent state (replicated across the group's 16 lanes)
  float hprev[4];
#pragma unroll
  for (int c = 0; c < 4; ++c) hprev[c] = h0[(size_t)b * UU + zc + c];

  if (tid < UU) Hb[tid >> 3][tid & 7] = h0[(size_t)b * UU + tid];

  // 2-deep prefetch ring (named regs)
  f4v czA, crA, chA, czB, crB, chB;
  {
    const float* gp = gxb + zc;
    czA = *(const f4v*)(gp);        crA = *(const f4v*)(gp + 128);        chA = *(const f4v*)(gp + 256);
    czB = *(const f4v*)(gp + G3U);  crB = *(const f4v*)(gp + G3U + 128);  chB = *(const f4v*)(gp + G3U + 256);
  }

  bar_lds();  // Hb init visible

#define STEP(T_IDX, PF, CZ, CR, CH)                                           \
  do {                                                                        \
    f4v curz = (CZ), curr = (CR), curh = (CH);                                \
    if (PF) {                                                                 \
      const float* gp_ = gxb + (size_t)((T_IDX) + 2) * G3U + zc;              \
      (CZ) = *(const f4v*)gp_;                                                \
      (CR) = *(const f4v*)(gp_ + 128);                                        \
      (CH) = *(const f4v*)(gp_ + 256);                                        \
    }                                                                         \
    /* ---- phase 1: r-gate critical path (z deferred) ---- */                \
    float4 h01_ = *(const float4*)&Hb[j][0];                                  \
    float4 h23_ = *(const float4*)&Hb[j][4];                                  \
    float2 hk_[4] = {make_float2(h01_.x, h01_.y), make_float2(h01_.z, h01_.w),\
                     make_float2(h23_.x, h23_.y), make_float2(h23_.z, h23_.w)};\
    float2 aZ0, aZ1, aZ2, aZ3, aR0, aR1, aR2, aR3;                            \
    aZ0 = aZ1 = aZ2 = aZ3 = aR0 = aR1 = aR2 = aR3 = make_float2(0.f, 0.f);    \
    _Pragma("unroll") for (int m = 0; m < 4; ++m) {                           \
      pk_fma(aR0, hk_[m], wR[0][m]);                                          \
      pk_fma(aR1, hk_[m], wR[1][m]);                                          \
      pk_fma(aR2, hk_[m], wR[2][m]);                                          \
      pk_fma(aR3, hk_[m], wR[3][m]);                                          \
      pk_fma(aZ0, hk_[m], wZ[0][m]);                                          \
      pk_fma(aZ1, hk_[m], wZ[1][m]);                                          \
      pk_fma(aZ2, hk_[m], wZ[2][m]);                                          \
      pk_fma(aZ3, hk_[m], wZ[3][m]);                                          \
    }                                                                         \
    float rs0_ = sig_(red16(aR0) + curr.x);                                   \
    float rs1_ = sig_(red16(aR1) + curr.y);                                   \
    float rs2_ = sig_(red16(aR2) + curr.z);                                   \
    float rs3_ = sig_(red16(aR3) + curr.w);                                   \
    if (j == 0)                                                               \
      *(f4v*)&Rb[g >> 1][4 * (g & 1)] =                                       \
          (f4v){rs0_ * hprev[0], rs1_ * hprev[1],                             \
                rs2_ * hprev[2], rs3_ * hprev[3]};                            \
    bar_lds(); /* B1: rh published */                                         \
    /* ---- phase 2: hh + deferred z + blend ---- */                          \
    float4 r01_ = *(const float4*)&Rb[j][0];                                  \
    float4 r23_ = *(const float4*)&Rb[j][4];                                  \
    /* z reductions execute under the Rb read shadow (register-only) */       \
    float zs0_ = sig_(red16(aZ0) + curz.x);                                   \
    float zs1_ = sig_(red16(aZ1) + curz.y);                                   \
    float zs2_ = sig_(red16(aZ2) + curz.z);                                   \
    float zs3_ = sig_(red16(aZ3) + curz.w);                                   \
    float2 rk_[4] = {make_float2(r01_.x, r01_.y), make_float2(r01_.z, r01_.w),\
                     make_float2(r23_.x, r23_.y), make_float2(r23_.z, r23_.w)};\
    float2 aH0, aH1, aH2, aH3;                                                \
    aH0 = aH1 = aH2 = aH3 = make_float2(0.f, 0.f);                            \
    _Pragma("unroll") for (int m = 0; m < 4; ++m) {                           \
      pk_fma(aH0, rk_[m], wH[0][m]);                                          \
      pk_fma(aH1, rk_[m], wH[1][m]);                                          \
      pk_fma(aH2, rk_[m], wH[2][m]);                                          \
      pk_fma(aH3, rk_[m], wH[3][m]);                                          \
    }                                                                         \
    float hh0_ = tanh_(red16(aH0) + curh.x);                                  \
    float hh1_ = tanh_(red16(aH1) + curh.y);                                  \
    float hh2_ = tanh_(red16(aH2) + curh.z);                                  \
    float hh3_ = tanh_(red16(aH3) + curh.w);                                  \
    float hn0_ = fmaf(zs0_, hprev[0] - hh0_, hh0_);                           \
    float hn1_ = fmaf(zs1_, hprev[1] - hh1_, hh1_);                           \
    float hn2_ = fmaf(zs2_, hprev[2] - hh2_, hh2_);                           \
    float hn3_ = fmaf(zs3_, hprev[3] - hh3_, hh3_);                           \
    hprev[0] = hn0_; hprev[1] = hn1_; hprev[2] = hn2_; hprev[3] = hn3_;       \
    if (j == 0) {                                                             \
      *(f4v*)&Hb[g >> 1][4 * (g & 1)] = (f4v){hn0_, hn1_, hn2_, hn3_};        \
      *(f4v*)&outb[(size_t)(T_IDX)*UU + zc] = (f4v){hn0_, hn1_, hn2_, hn3_};  \
    }                                                                         \
    bar_lds(); /* B2: h published */                                          \
  } while (0)

  // main loop: unconditional prefetch for steps 0..1995 (prefetch <= 1997)
  for (int t = 0; t < TT - 4; t += 2) {
    STEP(t, 1, czA, crA, chA);
    STEP(t + 1, 1, czB, crB, chB);
  }
  // tail: steps 1996..1999
  STEP(TT - 4, 1, czA, crA, chA);
  STEP(TT - 3, 1, czB, crB, chB);
  STEP(TT - 2, 0, czA, crA, chA);
  STEP(TT - 1, 0, czB, crB, chB);
#undef STEP
}

extern "C" void kernel_launch(void* const* d_in, const int* in_sizes, int n_in,
                              void* d_out, int out_size, void* d_ws, size_t ws_size,
                              hipStream_t stream) {
  const float* x = (const float*)d_in[0];
  const float* kern = (const float*)d_in[1];
  const float* rk = (const float*)d_in[2];
  const float* akern = (const float*)d_in[3];
  // d_in[4] attention_w, d_in[5] attention_u, d_in[7] attention_b, d_in[8] attention_v:
  // mathematically dead (softmax over singleton axis == 1, so z_hat == x_t).
  const float* bias = (const float*)d_in[6];
  const float* h0 = (const float*)d_in[9];
  float* out = (float*)d_out;
  float* gx = (float*)d_ws;  // [NROW][384] fp32 = 393,216,000 bytes

  gx_kernel<<<dim3(NROW / 64, G3U / 64), 256, 0, stream>>>(x, kern, akern, bias, gx);
  gru_rec<<<dim3(BB), 512, 0, stream>>>(gx, rk, h0, out);
}